// Round 6
// baseline (3287.548 us; speedup 1.0000x reference)
//
#include <hip/hip_runtime.h>

typedef float floatx4 __attribute__((ext_vector_type(4)));
typedef long longx2 __attribute__((ext_vector_type(2)));
typedef unsigned int u32;
typedef unsigned char u8;

#define MDIM 4096
#define HDIM 4096
#define IDIM 14336
#define FP8MAX 448.0f

// ---------------------------------------------------------------------------
// LDS tile geometry (BK=64): 128 rows x 64 B per buffer (8 KB).
// 16B chunk c of row r lives at slot (c ^ swz4(r)), swz4(r) = (r^(r>>2))&3.
// global_load_lds writes LINEARLY (uniform base + lane*16), so we pre-swizzle
// the per-lane GLOBAL source address instead (both-sides-or-neither rule).
// Ring-3 buffers with LITERAL bases (3-kb unrolled macro-iteration) so all
// LDS addressing folds to immediates (runtime ring index cost = R4 mistake).
// ---------------------------------------------------------------------------
__device__ __forceinline__ int swz4(int r) { return (r ^ (r >> 2)) & 3; }
__device__ __forceinline__ int frag_off(int row, int quad) {
  return (row << 6) + ((quad ^ swz4(row)) << 4);
}

__device__ __forceinline__ void gload16(const u8* g, u8* l) {
  __builtin_amdgcn_global_load_lds((const __attribute__((address_space(1))) u32*)g,
                                   (__attribute__((address_space(3))) u32*)l, 16, 0, 0);
}

#define VMW(n) asm volatile("s_waitcnt vmcnt(" #n ")" ::: "memory")
#define BAR() __builtin_amdgcn_s_barrier()

// ---------------------------------------------------------------------------
// Weight-dtype detection: 2 = fp32, 1 = bf16, 0 = raw fp8 bytes.
// ---------------------------------------------------------------------------
__global__ void detect_dtype(const unsigned int* __restrict__ w, int* __restrict__ flag) {
  if (threadIdx.x == 0 && blockIdx.x == 0) {
    bool f32 = true, b16 = true;
    for (int i = 0; i < 64; ++i) {
      const unsigned int v = w[i];
      if (v & 0xFFFFFu) f32 = false;
      if ((v & 0xFu) || ((v >> 16) & 0xFu)) b16 = false;
    }
    *flag = f32 ? 2 : (b16 ? 1 : 0);
  }
}

__device__ __forceinline__ float bfu(unsigned int bits16) {
  union { unsigned int u; float f; } c;
  c.u = bits16 << 16;
  return c.f;
}

__device__ __forceinline__ unsigned int pack2(unsigned int lo, unsigned int hi) {
  int pk = __builtin_amdgcn_cvt_pk_fp8_f32(bfu(lo & 0xFFFFu), bfu(lo >> 16), 0, false);
  pk = __builtin_amdgcn_cvt_pk_fp8_f32(bfu(hi & 0xFFFFu), bfu(hi >> 16), pk, true);
  return (unsigned int)pk;
}

__global__ __launch_bounds__(256) void conv_w(const void* __restrict__ src,
                                              unsigned char* __restrict__ dst,
                                              const int* __restrict__ flag_p) {
  const int flag = *flag_p;
  if (flag == 0) return;
  const long t = (long)blockIdx.x * 256 + threadIdx.x;  // 16 elements per thread
  uint4 out;
  if (flag == 2) {
    const float4* s = (const float4*)src;
    unsigned int o[4];
#pragma unroll
    for (int p = 0; p < 4; ++p) {
      const float4 v = s[t * 4 + p];
      int pk = __builtin_amdgcn_cvt_pk_fp8_f32(v.x, v.y, 0, false);
      pk = __builtin_amdgcn_cvt_pk_fp8_f32(v.z, v.w, pk, true);
      o[p] = (unsigned int)pk;
    }
    out = make_uint4(o[0], o[1], o[2], o[3]);
  } else {
    const uint4* s = (const uint4*)src;
    const uint4 a = s[t * 2], b = s[t * 2 + 1];
    out = make_uint4(pack2(a.x, a.y), pack2(a.z, a.w),
                     pack2(b.x, b.y), pack2(b.z, b.w));
  }
  ((uint4*)dst)[t] = out;
}

// ---------------------------------------------------------------------------
// Kernel 1: fake-quant activations. One wave per (row, 128-col group).
// ---------------------------------------------------------------------------
__global__ __launch_bounds__(256) void fq_act(const float* __restrict__ x,
                                              unsigned char* __restrict__ xq,
                                              float* __restrict__ xsT) {
  const int tid = threadIdx.x;
  const int lane = tid & 63, w = tid >> 6;
  const int g = blockIdx.x * 4 + w;
  const int row = g >> 5, kb = g & 31;

  const float2 v = ((const float2*)(x + (size_t)row * HDIM + kb * 128))[lane];
  float amax = fmaxf(fabsf(v.x), fabsf(v.y));
#pragma unroll
  for (int off = 1; off < 64; off <<= 1)
    amax = fmaxf(amax, __shfl_xor(amax, off, 64));

  const float scale = fmaxf(amax / FP8MAX, 1e-12f);
  const float q0 = fminf(fmaxf(v.x / scale, -FP8MAX), FP8MAX);
  const float q1 = fminf(fmaxf(v.y / scale, -FP8MAX), FP8MAX);
  const int pk = __builtin_amdgcn_cvt_pk_fp8_f32(q0, q1, 0, false);
  ((unsigned short*)(xq + (size_t)row * HDIM + kb * 128))[lane] = (unsigned short)(pk & 0xFFFF);
  if (lane == 0) xsT[(size_t)kb * MDIM + row] = scale;
}

// ---------------------------------------------------------------------------
// Kernel 2: fused gate/up blockwise-fp8 GEMM + silu*u + per-row-128 fake quant.
// ---------------------------------------------------------------------------
__global__ __launch_bounds__(256, 2)
void dual_gemm_silu_fq(const u8* __restrict__ xq, const float* __restrict__ xsT,
                       const u8* __restrict__ gw_cv, const u8* __restrict__ gw_raw,
                       const float* __restrict__ gs,
                       const u8* __restrict__ uw_cv, const u8* __restrict__ uw_raw,
                       const float* __restrict__ us,
                       u8* __restrict__ hq, float* __restrict__ hsT,
                       const int* __restrict__ flag_p, const int use_conv) {
  // 3 ring buffers x (A 8K | G 8K | U 8K); first 16 KB reused for output tile.
  __shared__ __align__(16) u8 lds[73728];

  const int tid = threadIdx.x;
  const int lane = tid & 63, wid = tid >> 6;
  const int quad = lane >> 4, l16 = lane & 15;

  // XCD-chunked swizzle: 3584 = 8 * 448 (bijective).
  const int bid0 = blockIdx.x;
  const int bid = (bid0 & 7) * 448 + (bid0 >> 3);
  const int mi = bid & 31, ni = bid >> 5;
  const size_t m0 = (size_t)mi << 7, n0 = (size_t)ni << 7;

  const u8* gw = gw_raw;
  const u8* uw = uw_raw;
  if (use_conv) {
    if (*flag_p != 0) { gw = gw_cv; uw = uw_cv; }
  }

  const u8* baseA = xq + m0 * HDIM;
  const u8* baseG = gw + n0 * HDIM;
  const u8* baseU = uw + n0 * HDIM;

  const int r16 = lane >> 2, slot = lane & 3;
  u32 srcoff[2], dstoff[2];
#pragma unroll
  for (int i = 0; i < 2; ++i) {
    const int row = wid * 32 + i * 16 + r16;
    srcoff[i] = (u32)(row * HDIM) + (u32)((slot ^ swz4(row)) << 4);
    dstoff[i] = (u32)(wid * 2048 + i * 1024);
  }

  int offA[2], offB[8];
#pragma unroll
  for (int mt = 0; mt < 2; ++mt) offA[mt] = frag_off(wid * 32 + mt * 16 + l16, quad);
#pragma unroll
  for (int nt = 0; nt < 8; ++nt) offB[nt] = frag_off(nt * 16 + l16, quad);

  floatx4 accG[2][8], accU[2][8];
#pragma unroll
  for (int mt = 0; mt < 2; ++mt)
#pragma unroll
    for (int nt = 0; nt < 8; ++nt) {
      accG[mt][nt] = {0.f, 0.f, 0.f, 0.f};
      accU[mt][nt] = {0.f, 0.f, 0.f, 0.f};
    }

  auto STG = [&](int goff, int lbase) {
#pragma unroll
    for (int i = 0; i < 2; ++i) {
      gload16(baseA + srcoff[i] + goff, &lds[lbase + dstoff[i]]);
      gload16(baseG + srcoff[i] + goff, &lds[lbase + 8192 + dstoff[i]]);
      gload16(baseU + srcoff[i] + goff, &lds[lbase + 16384 + dstoff[i]]);
    }
  };

  auto HLF = [&](int lbase) {
    const u8* bufA = lds + lbase;
    const u8* bufG = lds + lbase + 8192;
    const u8* bufU = lds + lbase + 16384;
    longx2 aF[2];
#pragma unroll
    for (int mt = 0; mt < 2; ++mt) aF[mt] = *(const longx2*)(bufA + offA[mt]);

    __builtin_amdgcn_s_setprio(1);
#pragma unroll
    for (int nt = 0; nt < 8; ++nt) {
      const longx2 bF = *(const longx2*)(bufG + offB[nt]);
#pragma unroll
      for (int mt = 0; mt < 2; ++mt) {
        accG[mt][nt] = __builtin_amdgcn_mfma_f32_16x16x32_fp8_fp8(aF[mt][0], bF[0], accG[mt][nt], 0, 0, 0);
        accG[mt][nt] = __builtin_amdgcn_mfma_f32_16x16x32_fp8_fp8(aF[mt][1], bF[1], accG[mt][nt], 0, 0, 0);
      }
    }
#pragma unroll
    for (int nt = 0; nt < 8; ++nt) {
      const longx2 bF = *(const longx2*)(bufU + offB[nt]);
#pragma unroll
      for (int mt = 0; mt < 2; ++mt) {
        accU[mt][nt] = __builtin_amdgcn_mfma_f32_16x16x32_fp8_fp8(aF[mt][0], bF[0], accU[mt][nt], 0, 0, 0);
        accU[mt][nt] = __builtin_amdgcn_mfma_f32_16x16x32_fp8_fp8(aF[mt][1], bF[1], accU[mt][nt], 0, 0, 0);
      }
    }
    __builtin_amdgcn_s_setprio(0);
  };

  // scale prefetch state (one kb ahead)
  const float* xsBase = xsT + m0 + wid * 32 + quad * 4;
  float4 xv0 = *(const float4*)(xsBase);
  float4 xv1 = *(const float4*)(xsBase + 16);
  float sgn = gs[ni * 32];
  float sun = us[ni * 32];

  float prX[2][4];
  float sgp = 1.f, sup = 1.f;
  int kb = 0;

  auto RESC = [&]() {
    float cx[2][4];
    cx[0][0] = xv0.x; cx[0][1] = xv0.y; cx[0][2] = xv0.z; cx[0][3] = xv0.w;
    cx[1][0] = xv1.x; cx[1][1] = xv1.y; cx[1][2] = xv1.z; cx[1][3] = xv1.w;
    const float sgc = sgn, suc = sun;
    if (kb) {
      const float rgs = sgp * __builtin_amdgcn_rcpf(sgc);
      const float rus = sup * __builtin_amdgcn_rcpf(suc);
#pragma unroll
      for (int mt = 0; mt < 2; ++mt)
#pragma unroll
        for (int r = 0; r < 4; ++r) {
          const float cm = prX[mt][r] * __builtin_amdgcn_rcpf(cx[mt][r]);
          const float rg = cm * rgs, ru = cm * rus;
#pragma unroll
          for (int nt = 0; nt < 8; ++nt) {
            accG[mt][nt][r] *= rg;
            accU[mt][nt][r] *= ru;
          }
        }
    }
#pragma unroll
    for (int mt = 0; mt < 2; ++mt)
#pragma unroll
      for (int r = 0; r < 4; ++r) prX[mt][r] = cx[mt][r];
    sgp = sgc; sup = suc;
    const int kbn = kb < 31 ? kb + 1 : 31;
    const float* xn = xsBase + (size_t)kbn * MDIM;
    xv0 = *(const float4*)(xn);
    xv1 = *(const float4*)(xn + 16);
    sgn = gs[ni * 32 + kbn];
    sun = us[ni * 32 + kbn];
  };

  STG(0, 0);       // half 0 -> buf 0
  STG(64, 24576);  // half 1 -> buf 1

  for (int kt = 0; kt < 10; ++kt) {
#pragma unroll
    for (int j = 0; j < 3; ++j) {
      constexpr int HB0[3] = {0, 49152, 24576};   // (2j)%3   * 24576
      constexpr int HB1[3] = {24576, 0, 49152};   // (2j+1)%3 * 24576
      constexpr int SB0[3] = {49152, 24576, 0};   // (2j+2)%3 * 24576
      constexpr int SB1[3] = {0, 49152, 24576};   // (2j+3)%3 * 24576
      STG((2 * j + 2) * 64, SB0[j]);
      RESC();                       // rescale under the in-flight stage
      VMW(12); BAR();
      HLF(HB0[j]);
      BAR();
      STG((2 * j + 3) * 64, SB1[j]);
      VMW(12); BAR();
      HLF(HB1[j]);
      BAR();
      ++kb;
    }
    srcoff[0] += 384;
    srcoff[1] += 384;
  }
  // tail: kb = 30 (halves 60,61 -> bufs 0,1; stage halves 62,63 -> bufs 2,0)
  STG(128, 49152);
  RESC();
  VMW(12); BAR(); HLF(0); BAR();
  STG(192, 0);
  VMW(12); BAR(); HLF(24576); BAR();
  ++kb;
  // kb = 31 (halves 62,63 -> bufs 2,0; no stages)
  RESC();
  VMW(6); BAR(); HLF(49152); BAR();
  VMW(0); BAR(); HLF(0); BAR();

  // undo running-scale
#pragma unroll
  for (int mt = 0; mt < 2; ++mt)
#pragma unroll
    for (int r = 0; r < 4; ++r) {
      const float fg = prX[mt][r] * sgp;
      const float fu = prX[mt][r] * sup;
#pragma unroll
      for (int nt = 0; nt < 8; ++nt) {
        accG[mt][nt][r] *= fg;
        accU[mt][nt][r] *= fu;
      }
    }

  // ---- epilogue: h = silu(g)*u, per-row fake quant over this 128-col group.
  u8* ot = lds;  // 16 KB, safe: all waves past final barrier
#pragma unroll
  for (int mt = 0; mt < 2; ++mt) {
    float h[8][4];
    float amax[4] = {0.f, 0.f, 0.f, 0.f};
#pragma unroll
    for (int nt = 0; nt < 8; ++nt)
#pragma unroll
      for (int r = 0; r < 4; ++r) {
        const float gv = accG[mt][nt][r];
        const float uv = accU[mt][nt][r];
        const float hv = (gv / (1.f + __expf(-gv))) * uv;
        h[nt][r] = hv;
        amax[r] = fmaxf(amax[r], fabsf(hv));
      }
#pragma unroll
    for (int off = 1; off < 16; off <<= 1)
#pragma unroll
      for (int r = 0; r < 4; ++r)
        amax[r] = fmaxf(amax[r], __shfl_xor(amax[r], off, 64));

    float scale[4];
#pragma unroll
    for (int r = 0; r < 4; ++r) scale[r] = fmaxf(amax[r] / FP8MAX, 1e-12f);

    const int rowl = wid * 32 + mt * 16 + quad * 4;
    if (l16 == 0) {
#pragma unroll
      for (int r = 0; r < 4; ++r)
        hsT[(size_t)ni * MDIM + m0 + rowl + r] = scale[r];
    }
#pragma unroll
    for (int nt = 0; nt < 8; ++nt)
#pragma unroll
      for (int r = 0; r < 4; ++r) {
        const float q = fminf(fmaxf(h[nt][r] / scale[r], -FP8MAX), FP8MAX);
        const int pk = __builtin_amdgcn_cvt_pk_fp8_f32(q, 0.f, 0, false);
        ot[(rowl + r) * 128 + nt * 16 + l16] = (u8)(pk & 0xFF);
      }
  }
  __syncthreads();
  {
    const int row = tid >> 1, half = tid & 1;
    const uint4* s = (const uint4*)(ot + row * 128 + half * 64);
    uint4* d = (uint4*)(hq + (m0 + row) * IDIM + n0 + half * 64);
#pragma unroll
    for (int i = 0; i < 4; ++i) d[i] = s[i];
  }
}

// ---------------------------------------------------------------------------
// Kernel 3: down projection. Same literal-ring pipeline, 112 kbs.
// ---------------------------------------------------------------------------
__global__ __launch_bounds__(256, 2)
void gemm_down(const u8* __restrict__ hq, const float* __restrict__ hsT,
               const u8* __restrict__ dw_cv, const u8* __restrict__ dw_raw,
               const float* __restrict__ dsc, float* __restrict__ out,
               const int* __restrict__ flag_p, const int use_conv) {
  __shared__ __align__(16) u8 lds[49152];  // 3 ring bufs x (A 8K | B 8K)

  const int tid = threadIdx.x;
  const int lane = tid & 63, wid = tid >> 6;
  const int quad = lane >> 4, l16 = lane & 15;

  const int bid0 = blockIdx.x;
  const int bid = (bid0 & 7) * 128 + (bid0 >> 3);  // 1024 = 8 * 128
  const int mi = bid & 31, ni = bid >> 5;
  const size_t m0 = (size_t)mi << 7, n0 = (size_t)ni << 7;

  const u8* dw = dw_raw;
  if (use_conv) {
    if (*flag_p != 0) dw = dw_cv;
  }

  const u8* baseA = hq + m0 * IDIM;
  const u8* baseB = dw + n0 * IDIM;

  const int r16 = lane >> 2, slot = lane & 3;
  u32 srcoff[2], dstoff[2];
#pragma unroll
  for (int i = 0; i < 2; ++i) {
    const int row = wid * 32 + i * 16 + r16;
    srcoff[i] = (u32)(row * IDIM) + (u32)((slot ^ swz4(row)) << 4);
    dstoff[i] = (u32)(wid * 2048 + i * 1024);
  }

  int offA[2], offB[8];
#pragma unroll
  for (int mt = 0; mt < 2; ++mt) offA[mt] = frag_off(wid * 32 + mt * 16 + l16, quad);
#pragma unroll
  for (int nt = 0; nt < 8; ++nt) offB[nt] = frag_off(nt * 16 + l16, quad);

  floatx4 acc[2][8];
#pragma unroll
  for (int mt = 0; mt < 2; ++mt)
#pragma unroll
    for (int nt = 0; nt < 8; ++nt) acc[mt][nt] = {0.f, 0.f, 0.f, 0.f};

  auto STG = [&](int goff, int lbase) {
#pragma unroll
    for (int i = 0; i < 2; ++i) {
      gload16(baseA + srcoff[i] + goff, &lds[lbase + dstoff[i]]);
      gload16(baseB + srcoff[i] + goff, &lds[lbase + 8192 + dstoff[i]]);
    }
  };

  auto HLF = [&](int lbase) {
    const u8* lb = lds + lbase;
    longx2 aF[2];
#pragma unroll
    for (int mt = 0; mt < 2; ++mt) aF[mt] = *(const longx2*)(lb + offA[mt]);
    __builtin_amdgcn_s_setprio(1);
#pragma unroll
    for (int nt = 0; nt < 8; ++nt) {
      const longx2 bF = *(const longx2*)(lb + 8192 + offB[nt]);
#pragma unroll
      for (int mt = 0; mt < 2; ++mt) {
        acc[mt][nt] = __builtin_amdgcn_mfma_f32_16x16x32_fp8_fp8(aF[mt][0], bF[0], acc[mt][nt], 0, 0, 0);
        acc[mt][nt] = __builtin_amdgcn_mfma_f32_16x16x32_fp8_fp8(aF[mt][1], bF[1], acc[mt][nt], 0, 0, 0);
      }
    }
    __builtin_amdgcn_s_setprio(0);
  };

  const float* hsBase = hsT + m0 + wid * 32 + quad * 4;
  float4 xv0 = *(const float4*)(hsBase);
  float4 xv1 = *(const float4*)(hsBase + 16);
  float sdn = dsc[ni * 112];

  float prX[2][4];
  float sdp = 1.f;
  int kb = 0;

  auto RESC = [&]() {
    float cx[2][4];
    cx[0][0] = xv0.x; cx[0][1] = xv0.y; cx[0][2] = xv0.z; cx[0][3] = xv0.w;
    cx[1][0] = xv1.x; cx[1][1] = xv1.y; cx[1][2] = xv1.z; cx[1][3] = xv1.w;
    const float sdc = sdn;
    if (kb) {
      const float rds = sdp * __builtin_amdgcn_rcpf(sdc);
#pragma unroll
      for (int mt = 0; mt < 2; ++mt)
#pragma unroll
        for (int r = 0; r < 4; ++r) {
          const float rr = prX[mt][r] * __builtin_amdgcn_rcpf(cx[mt][r]) * rds;
#pragma unroll
          for (int nt = 0; nt < 8; ++nt) acc[mt][nt][r] *= rr;
        }
    }
#pragma unroll
    for (int mt = 0; mt < 2; ++mt)
#pragma unroll
      for (int r = 0; r < 4; ++r) prX[mt][r] = cx[mt][r];
    sdp = sdc;
    const int kbn = kb < 111 ? kb + 1 : 111;
    const float* xn = hsBase + (size_t)kbn * MDIM;
    xv0 = *(const float4*)(xn);
    xv1 = *(const float4*)(xn + 16);
    sdn = dsc[ni * 112 + kbn];
  };

  STG(0, 0);       // half 0 -> buf 0
  STG(64, 16384);  // half 1 -> buf 1

  for (int kt = 0; kt < 37; ++kt) {
#pragma unroll
    for (int j = 0; j < 3; ++j) {
      constexpr int HB0[3] = {0, 32768, 16384};
      constexpr int HB1[3] = {16384, 0, 32768};
      constexpr int SB0[3] = {32768, 16384, 0};
      constexpr int SB1[3] = {0, 32768, 16384};
      STG((2 * j + 2) * 64, SB0[j]);
      RESC();
      VMW(8); BAR();
      HLF(HB0[j]);
      BAR();
      STG((2 * j + 3) * 64, SB1[j]);
      VMW(8); BAR();
      HLF(HB1[j]);
      BAR();
      ++kb;
    }
    srcoff[0] += 384;
    srcoff[1] += 384;
  }
  // tail: kb = 111 (halves 222,223 -> bufs 0,1; no stages)
  RESC();
  VMW(4); BAR(); HLF(0); BAR();
  VMW(0); BAR(); HLF(16384); BAR();

#pragma unroll
  for (int mt = 0; mt < 2; ++mt) {
    const int rowl = wid * 32 + mt * 16 + quad * 4;
#pragma unroll
    for (int nt = 0; nt < 8; ++nt)
#pragma unroll
      for (int r = 0; r < 4; ++r)
        out[(m0 + rowl + r) * (size_t)HDIM + n0 + nt * 16 + l16] =
            acc[mt][nt][r] * prX[mt][r] * sdp;
  }
}

// ---------------------------------------------------------------------------
extern "C" void kernel_launch(void* const* d_in, const int* in_sizes, int n_in,
                              void* d_out, int out_size, void* d_ws, size_t ws_size,
                              hipStream_t stream) {
  const float* x   = (const float*)d_in[0];
  const void* gw_s = d_in[1];
  const float* gs  = (const float*)d_in[2];
  const void* uw_s = d_in[3];
  const float* us  = (const float*)d_in[4];
  const void* dw_s = d_in[5];
  const float* dsc = (const float*)d_in[6];
  float* out       = (float*)d_out;

  const size_t NW = (size_t)IDIM * HDIM;  // 58,720,256 elements per weight

  unsigned char* ws = (unsigned char*)d_ws;
  unsigned char* xq = ws;                         // 16 MB
  float* xsT = (float*)(ws + 16777216);           // 512 KB
  unsigned char* hq  = ws + 17301504;             // 56 MB
  float* hsT = (float*)(ws + 76021760);           // 1.75 MB
  unsigned char* gwq = ws + 77856768;             // 56 MB
  unsigned char* uwq = ws + 136577024;            // 56 MB
  unsigned char* dwq = gwq;                       // reuse gate slot after dual_gemm
  int* flag = (int*)(ws + 195297280);

  const bool fits = ws_size >= (size_t)195297284;
  const int use_conv = fits ? 1 : 0;

  const int convBlocks = (int)(NW / (16 * 256));  // 14336, exact

  if (fits) {
    detect_dtype<<<1, 64, 0, stream>>>((const unsigned int*)gw_s, flag);
    conv_w<<<convBlocks, 256, 0, stream>>>(gw_s, gwq, flag);
    conv_w<<<convBlocks, 256, 0, stream>>>(uw_s, uwq, flag);
  }
  fq_act<<<(MDIM * (HDIM / 128)) / 4, 256, 0, stream>>>(x, xq, xsT);
  dual_gemm_silu_fq<<<(MDIM / 128) * (IDIM / 128), 256, 0, stream>>>(
      xq, xsT, gwq, (const unsigned char*)gw_s, gs,
      uwq, (const unsigned char*)uw_s, us, hq, hsT, flag, use_conv);
  if (fits) {
    conv_w<<<convBlocks, 256, 0, stream>>>(dw_s, dwq, flag);
  }
  gemm_down<<<(MDIM / 128) * (HDIM / 128), 256, 0, stream>>>(
      hq, hsT, dwq, (const unsigned char*)dw_s, dsc, out, flag, use_conv);
}

// Round 8
// 1765.042 us; speedup vs baseline: 1.8626x; 1.8626x over previous
//
#include <hip/hip_runtime.h>

typedef float floatx4 __attribute__((ext_vector_type(4)));
typedef long longx2 __attribute__((ext_vector_type(2)));
typedef unsigned int u32;
typedef unsigned char u8;

#define MDIM 4096
#define HDIM 4096
#define IDIM 14336
#define FP8MAX 448.0f

// ---------------------------------------------------------------------------
// LDS tile geometry (BK=64): 128 rows x 64 B per buffer (8 KB).
// 16B chunk c of row r lives at slot (c ^ swz4(r)), swz4(r) = (r^(r>>2))&3.
// global_load_lds writes LINEARLY (uniform base + lane*16), so we pre-swizzle
// the per-lane GLOBAL source address instead (both-sides-or-neither rule).
// Ring-3 buffers with RUNTIME index (literal-unroll spilled: R6 = 4 GB scratch).
// ---------------------------------------------------------------------------
__device__ __forceinline__ int swz4(int r) { return (r ^ (r >> 2)) & 3; }
__device__ __forceinline__ int frag_off(int row, int quad) {
  return (row << 6) + ((quad ^ swz4(row)) << 4);
}

__device__ __forceinline__ void gload16(const u8* g, u8* l) {
  __builtin_amdgcn_global_load_lds((const __attribute__((address_space(1))) u32*)g,
                                   (__attribute__((address_space(3))) u32*)l, 16, 0, 0);
}

#define VMW(n) asm volatile("s_waitcnt vmcnt(" #n ")" ::: "memory")
#define BAR() __builtin_amdgcn_s_barrier()

// ---------------------------------------------------------------------------
// Weight-dtype detection: 2 = fp32, 1 = bf16, 0 = raw fp8 bytes.
// ---------------------------------------------------------------------------
__global__ void detect_dtype(const unsigned int* __restrict__ w, int* __restrict__ flag) {
  if (threadIdx.x == 0 && blockIdx.x == 0) {
    bool f32 = true, b16 = true;
    for (int i = 0; i < 64; ++i) {
      const unsigned int v = w[i];
      if (v & 0xFFFFFu) f32 = false;
      if ((v & 0xFu) || ((v >> 16) & 0xFu)) b16 = false;
    }
    *flag = f32 ? 2 : (b16 ? 1 : 0);
  }
}

__device__ __forceinline__ float bfu(unsigned int bits16) {
  union { unsigned int u; float f; } c;
  c.u = bits16 << 16;
  return c.f;
}

__device__ __forceinline__ unsigned int pack2(unsigned int lo, unsigned int hi) {
  int pk = __builtin_amdgcn_cvt_pk_fp8_f32(bfu(lo & 0xFFFFu), bfu(lo >> 16), 0, false);
  pk = __builtin_amdgcn_cvt_pk_fp8_f32(bfu(hi & 0xFFFFu), bfu(hi >> 16), pk, true);
  return (unsigned int)pk;
}

__global__ __launch_bounds__(256) void conv_w(const void* __restrict__ src,
                                              unsigned char* __restrict__ dst,
                                              const int* __restrict__ flag_p) {
  const int flag = *flag_p;
  if (flag == 0) return;
  const long t = (long)blockIdx.x * 256 + threadIdx.x;  // 16 elements per thread
  uint4 out;
  if (flag == 2) {
    const float4* s = (const float4*)src;
    unsigned int o[4];
#pragma unroll
    for (int p = 0; p < 4; ++p) {
      const float4 v = s[t * 4 + p];
      int pk = __builtin_amdgcn_cvt_pk_fp8_f32(v.x, v.y, 0, false);
      pk = __builtin_amdgcn_cvt_pk_fp8_f32(v.z, v.w, pk, true);
      o[p] = (unsigned int)pk;
    }
    out = make_uint4(o[0], o[1], o[2], o[3]);
  } else {
    const uint4* s = (const uint4*)src;
    const uint4 a = s[t * 2], b = s[t * 2 + 1];
    out = make_uint4(pack2(a.x, a.y), pack2(a.z, a.w),
                     pack2(b.x, b.y), pack2(b.z, b.w));
  }
  ((uint4*)dst)[t] = out;
}

// ---------------------------------------------------------------------------
// Kernel 1: fake-quant activations. One wave per (row, 128-col group).
// ---------------------------------------------------------------------------
__global__ __launch_bounds__(256) void fq_act(const float* __restrict__ x,
                                              unsigned char* __restrict__ xq,
                                              float* __restrict__ xsT) {
  const int tid = threadIdx.x;
  const int lane = tid & 63, w = tid >> 6;
  const int g = blockIdx.x * 4 + w;
  const int row = g >> 5, kb = g & 31;

  const float2 v = ((const float2*)(x + (size_t)row * HDIM + kb * 128))[lane];
  float amax = fmaxf(fabsf(v.x), fabsf(v.y));
#pragma unroll
  for (int off = 1; off < 64; off <<= 1)
    amax = fmaxf(amax, __shfl_xor(amax, off, 64));

  const float scale = fmaxf(amax / FP8MAX, 1e-12f);
  const float q0 = fminf(fmaxf(v.x / scale, -FP8MAX), FP8MAX);
  const float q1 = fminf(fmaxf(v.y / scale, -FP8MAX), FP8MAX);
  const int pk = __builtin_amdgcn_cvt_pk_fp8_f32(q0, q1, 0, false);
  ((unsigned short*)(xq + (size_t)row * HDIM + kb * 128))[lane] = (unsigned short)(pk & 0xFFFF);
  if (lane == 0) xsT[(size_t)kb * MDIM + row] = scale;
}

// ---------------------------------------------------------------------------
// Kernel 2: fused gate/up blockwise-fp8 GEMM + silu*u + per-row-128 fake quant.
// R4 structure (runtime-cb ring-3) + rcp rescale + vector (pk) acc muls +
// STG-before-RESC so DMA flies under the rescale VALU.
// ---------------------------------------------------------------------------
__global__ __launch_bounds__(256, 2)
void dual_gemm_silu_fq(const u8* __restrict__ xq, const float* __restrict__ xsT,
                       const u8* __restrict__ gw_cv, const u8* __restrict__ gw_raw,
                       const float* __restrict__ gs,
                       const u8* __restrict__ uw_cv, const u8* __restrict__ uw_raw,
                       const float* __restrict__ us,
                       u8* __restrict__ hq, float* __restrict__ hsT,
                       const int* __restrict__ flag_p, const int use_conv) {
  // 3 ring buffers x (A 8K | G 8K | U 8K); first 16 KB reused for output tile.
  __shared__ __align__(16) u8 lds[73728];

  const int tid = threadIdx.x;
  const int lane = tid & 63, wid = tid >> 6;
  const int quad = lane >> 4, l16 = lane & 15;

  // XCD-chunked swizzle: 3584 = 8 * 448 (bijective).
  const int bid0 = blockIdx.x;
  const int bid = (bid0 & 7) * 448 + (bid0 >> 3);
  const int mi = bid & 31, ni = bid >> 5;
  const size_t m0 = (size_t)mi << 7, n0 = (size_t)ni << 7;

  const u8* gw = gw_raw;
  const u8* uw = uw_raw;
  if (use_conv) {
    if (*flag_p != 0) { gw = gw_cv; uw = uw_cv; }
  }

  const u8* baseA = xq + m0 * HDIM;
  const u8* baseG = gw + n0 * HDIM;
  const u8* baseU = uw + n0 * HDIM;

  const int r16 = lane >> 2, slot = lane & 3;
  u32 srcoff[2], dstoff[2];
#pragma unroll
  for (int i = 0; i < 2; ++i) {
    const int row = wid * 32 + i * 16 + r16;
    srcoff[i] = (u32)(row * HDIM) + (u32)((slot ^ swz4(row)) << 4);
    dstoff[i] = (u32)(wid * 2048 + i * 1024);
  }

  int offA[2], offB[8];
#pragma unroll
  for (int mt = 0; mt < 2; ++mt) offA[mt] = frag_off(wid * 32 + mt * 16 + l16, quad);
#pragma unroll
  for (int nt = 0; nt < 8; ++nt) offB[nt] = frag_off(nt * 16 + l16, quad);

  floatx4 accG[2][8], accU[2][8];
#pragma unroll
  for (int mt = 0; mt < 2; ++mt)
#pragma unroll
    for (int nt = 0; nt < 8; ++nt) {
      accG[mt][nt] = {0.f, 0.f, 0.f, 0.f};
      accU[mt][nt] = {0.f, 0.f, 0.f, 0.f};
    }

  auto STAGE = [&](int t, int b) {
    const u32 ko = (u32)t << 6;
    u8* lb = lds + b * 24576;
#pragma unroll
    for (int i = 0; i < 2; ++i) {
      gload16(baseA + srcoff[i] + ko, lb + dstoff[i]);
      gload16(baseG + srcoff[i] + ko, lb + 8192u + dstoff[i]);
      gload16(baseU + srcoff[i] + ko, lb + 16384u + dstoff[i]);
    }
  };

  auto HALF = [&](int b) {
    const u8* lb = lds + b * 24576;
    const u8* bufA = lb;
    const u8* bufG = lb + 8192;
    const u8* bufU = lb + 16384;
    longx2 aF[2];
#pragma unroll
    for (int mt = 0; mt < 2; ++mt) aF[mt] = *(const longx2*)(bufA + offA[mt]);

    __builtin_amdgcn_s_setprio(1);
#pragma unroll
    for (int nt = 0; nt < 8; ++nt) {
      const longx2 bF = *(const longx2*)(bufG + offB[nt]);
#pragma unroll
      for (int mt = 0; mt < 2; ++mt) {
        accG[mt][nt] = __builtin_amdgcn_mfma_f32_16x16x32_fp8_fp8(aF[mt][0], bF[0], accG[mt][nt], 0, 0, 0);
        accG[mt][nt] = __builtin_amdgcn_mfma_f32_16x16x32_fp8_fp8(aF[mt][1], bF[1], accG[mt][nt], 0, 0, 0);
      }
    }
#pragma unroll
    for (int nt = 0; nt < 8; ++nt) {
      const longx2 bF = *(const longx2*)(bufU + offB[nt]);
#pragma unroll
      for (int mt = 0; mt < 2; ++mt) {
        accU[mt][nt] = __builtin_amdgcn_mfma_f32_16x16x32_fp8_fp8(aF[mt][0], bF[0], accU[mt][nt], 0, 0, 0);
        accU[mt][nt] = __builtin_amdgcn_mfma_f32_16x16x32_fp8_fp8(aF[mt][1], bF[1], accU[mt][nt], 0, 0, 0);
      }
    }
    __builtin_amdgcn_s_setprio(0);
  };

  // scale prefetch state (one kb ahead); 16B-aligned vector loads
  const float* xsBase = xsT + m0 + wid * 32 + quad * 4;
  floatx4 xv0 = *(const floatx4*)(xsBase);
  floatx4 xv1 = *(const floatx4*)(xsBase + 16);
  float sgn = gs[ni * 32];
  float sun = us[ni * 32];

  STAGE(0, 0);
  STAGE(1, 1);

  floatx4 prX[2];
  float sgp = 1.f, sup = 1.f;
  int cb = 0;

  for (int kb = 0; kb < 32; ++kb) {
    // ---- half 1 (consume t = 2kb) ----
    {
      int sb = cb + 2; if (sb >= 3) sb -= 3;
      if (kb < 31) STAGE(2 * kb + 2, sb);
      // rescale under the in-flight stage DMA
      const floatx4 cx0 = xv0, cx1 = xv1;
      const float sgc = sgn, suc = sun;
      if (kb) {
        const float rgs = sgp * __builtin_amdgcn_rcpf(sgc);
        const float rus = sup * __builtin_amdgcn_rcpf(suc);
        floatx4 i0, i1;
#pragma unroll
        for (int r = 0; r < 4; ++r) {
          i0[r] = __builtin_amdgcn_rcpf(cx0[r]);
          i1[r] = __builtin_amdgcn_rcpf(cx1[r]);
        }
        const floatx4 cm0 = prX[0] * i0, cm1 = prX[1] * i1;
        const floatx4 rg0 = cm0 * rgs, ru0 = cm0 * rus;
        const floatx4 rg1 = cm1 * rgs, ru1 = cm1 * rus;
#pragma unroll
        for (int nt = 0; nt < 8; ++nt) {
          accG[0][nt] *= rg0;
          accG[1][nt] *= rg1;
          accU[0][nt] *= ru0;
          accU[1][nt] *= ru1;
        }
      }
      prX[0] = cx0; prX[1] = cx1;
      sgp = sgc; sup = suc;
      const int kbn = kb < 31 ? kb + 1 : 31;
      const float* xn = xsBase + (size_t)kbn * MDIM;
      xv0 = *(const floatx4*)(xn);
      xv1 = *(const floatx4*)(xn + 16);
      sgn = gs[ni * 32 + kbn];
      sun = us[ni * 32 + kbn];

      if (kb < 31) { VMW(12); } else { VMW(6); }
      BAR();
      HALF(cb);
      BAR();
      if (++cb >= 3) cb = 0;
    }
    // ---- half 2 (consume t = 2kb+1) ----
    {
      int sb = cb + 2; if (sb >= 3) sb -= 3;
      if (kb < 31) {
        STAGE(2 * kb + 3, sb);
        VMW(12);
      } else {
        VMW(0);
      }
      BAR();
      HALF(cb);
      BAR();
      if (++cb >= 3) cb = 0;
    }
  }

  // undo running-scale
#pragma unroll
  for (int mt = 0; mt < 2; ++mt) {
    const floatx4 fg = prX[mt] * sgp;
    const floatx4 fu = prX[mt] * sup;
#pragma unroll
    for (int nt = 0; nt < 8; ++nt) {
      accG[mt][nt] *= fg;
      accU[mt][nt] *= fu;
    }
  }

  // ---- epilogue: h = silu(g)*u, per-row fake quant over this 128-col group.
  u8* ot = lds;  // 16 KB, safe: all waves past final barrier
#pragma unroll
  for (int mt = 0; mt < 2; ++mt) {
    float h[8][4];
    float amax[4] = {0.f, 0.f, 0.f, 0.f};
#pragma unroll
    for (int nt = 0; nt < 8; ++nt)
#pragma unroll
      for (int r = 0; r < 4; ++r) {
        const float gv = accG[mt][nt][r];
        const float uv = accU[mt][nt][r];
        const float hv = (gv / (1.f + __expf(-gv))) * uv;
        h[nt][r] = hv;
        amax[r] = fmaxf(amax[r], fabsf(hv));
      }
#pragma unroll
    for (int off = 1; off < 16; off <<= 1)
#pragma unroll
      for (int r = 0; r < 4; ++r)
        amax[r] = fmaxf(amax[r], __shfl_xor(amax[r], off, 64));

    float scale[4];
#pragma unroll
    for (int r = 0; r < 4; ++r) scale[r] = fmaxf(amax[r] / FP8MAX, 1e-12f);

    const int rowl = wid * 32 + mt * 16 + quad * 4;
    if (l16 == 0) {
#pragma unroll
      for (int r = 0; r < 4; ++r)
        hsT[(size_t)ni * MDIM + m0 + rowl + r] = scale[r];
    }
#pragma unroll
    for (int nt = 0; nt < 8; ++nt)
#pragma unroll
      for (int r = 0; r < 4; ++r) {
        const float q = fminf(fmaxf(h[nt][r] / scale[r], -FP8MAX), FP8MAX);
        const int pk = __builtin_amdgcn_cvt_pk_fp8_f32(q, 0.f, 0, false);
        ot[(rowl + r) * 128 + nt * 16 + l16] = (u8)(pk & 0xFF);
      }
  }
  __syncthreads();
  {
    const int row = tid >> 1, half = tid & 1;
    const uint4* s = (const uint4*)(ot + row * 128 + half * 64);
    uint4* d = (uint4*)(hq + (m0 + row) * IDIM + n0 + half * 64);
#pragma unroll
    for (int i = 0; i < 4; ++i) d[i] = s[i];
  }
}

// ---------------------------------------------------------------------------
// Kernel 3: down projection. Same R4 ring pipeline + rcp/vector rescale.
// ---------------------------------------------------------------------------
__global__ __launch_bounds__(256, 2)
void gemm_down(const u8* __restrict__ hq, const float* __restrict__ hsT,
               const u8* __restrict__ dw_cv, const u8* __restrict__ dw_raw,
               const float* __restrict__ dsc, float* __restrict__ out,
               const int* __restrict__ flag_p, const int use_conv) {
  __shared__ __align__(16) u8 lds[49152];  // 3 ring bufs x (A 8K | B 8K)

  const int tid = threadIdx.x;
  const int lane = tid & 63, wid = tid >> 6;
  const int quad = lane >> 4, l16 = lane & 15;

  const int bid0 = blockIdx.x;
  const int bid = (bid0 & 7) * 128 + (bid0 >> 3);  // 1024 = 8 * 128
  const int mi = bid & 31, ni = bid >> 5;
  const size_t m0 = (size_t)mi << 7, n0 = (size_t)ni << 7;

  const u8* dw = dw_raw;
  if (use_conv) {
    if (*flag_p != 0) dw = dw_cv;
  }

  const u8* baseA = hq + m0 * IDIM;
  const u8* baseB = dw + n0 * IDIM;

  const int r16 = lane >> 2, slot = lane & 3;
  u32 srcoff[2], dstoff[2];
#pragma unroll
  for (int i = 0; i < 2; ++i) {
    const int row = wid * 32 + i * 16 + r16;
    srcoff[i] = (u32)(row * IDIM) + (u32)((slot ^ swz4(row)) << 4);
    dstoff[i] = (u32)(wid * 2048 + i * 1024);
  }

  int offA[2], offB[8];
#pragma unroll
  for (int mt = 0; mt < 2; ++mt) offA[mt] = frag_off(wid * 32 + mt * 16 + l16, quad);
#pragma unroll
  for (int nt = 0; nt < 8; ++nt) offB[nt] = frag_off(nt * 16 + l16, quad);

  floatx4 acc[2][8];
#pragma unroll
  for (int mt = 0; mt < 2; ++mt)
#pragma unroll
    for (int nt = 0; nt < 8; ++nt) acc[mt][nt] = {0.f, 0.f, 0.f, 0.f};

  auto STAGE = [&](int t, int b) {
    const u32 ko = (u32)t << 6;
    u8* lb = lds + b * 16384;
#pragma unroll
    for (int i = 0; i < 2; ++i) {
      gload16(baseA + srcoff[i] + ko, lb + dstoff[i]);
      gload16(baseB + srcoff[i] + ko, lb + 8192u + dstoff[i]);
    }
  };

  auto HALF = [&](int b) {
    const u8* lb = lds + b * 16384;
    longx2 aF[2];
#pragma unroll
    for (int mt = 0; mt < 2; ++mt) aF[mt] = *(const longx2*)(lb + offA[mt]);
    __builtin_amdgcn_s_setprio(1);
#pragma unroll
    for (int nt = 0; nt < 8; ++nt) {
      const longx2 bF = *(const longx2*)(lb + 8192 + offB[nt]);
#pragma unroll
      for (int mt = 0; mt < 2; ++mt) {
        acc[mt][nt] = __builtin_amdgcn_mfma_f32_16x16x32_fp8_fp8(aF[mt][0], bF[0], acc[mt][nt], 0, 0, 0);
        acc[mt][nt] = __builtin_amdgcn_mfma_f32_16x16x32_fp8_fp8(aF[mt][1], bF[1], acc[mt][nt], 0, 0, 0);
      }
    }
    __builtin_amdgcn_s_setprio(0);
  };

  const float* hsBase = hsT + m0 + wid * 32 + quad * 4;
  floatx4 xv0 = *(const floatx4*)(hsBase);
  floatx4 xv1 = *(const floatx4*)(hsBase + 16);
  float sdn = dsc[ni * 112];

  STAGE(0, 0);
  STAGE(1, 1);

  floatx4 prX[2];
  float sdp = 1.f;
  int cb = 0;

  for (int kb = 0; kb < 112; ++kb) {
    // ---- half 1 ----
    {
      int sb = cb + 2; if (sb >= 3) sb -= 3;
      if (kb < 111) STAGE(2 * kb + 2, sb);
      const floatx4 cx0 = xv0, cx1 = xv1;
      const float sdc = sdn;
      if (kb) {
        const float rds = sdp * __builtin_amdgcn_rcpf(sdc);
        floatx4 i0, i1;
#pragma unroll
        for (int r = 0; r < 4; ++r) {
          i0[r] = __builtin_amdgcn_rcpf(cx0[r]);
          i1[r] = __builtin_amdgcn_rcpf(cx1[r]);
        }
        const floatx4 r0 = prX[0] * i0 * rds;
        const floatx4 r1 = prX[1] * i1 * rds;
#pragma unroll
        for (int nt = 0; nt < 8; ++nt) {
          acc[0][nt] *= r0;
          acc[1][nt] *= r1;
        }
      }
      prX[0] = cx0; prX[1] = cx1;
      sdp = sdc;
      const int kbn = kb < 111 ? kb + 1 : 111;
      const float* xn = hsBase + (size_t)kbn * MDIM;
      xv0 = *(const floatx4*)(xn);
      xv1 = *(const floatx4*)(xn + 16);
      sdn = dsc[ni * 112 + kbn];

      if (kb < 111) { VMW(8); } else { VMW(4); }
      BAR();
      HALF(cb);
      BAR();
      if (++cb >= 3) cb = 0;
    }
    // ---- half 2 ----
    {
      int sb = cb + 2; if (sb >= 3) sb -= 3;
      if (kb < 111) {
        STAGE(2 * kb + 3, sb);
        VMW(8);
      } else {
        VMW(0);
      }
      BAR();
      HALF(cb);
      BAR();
      if (++cb >= 3) cb = 0;
    }
  }

#pragma unroll
  for (int mt = 0; mt < 2; ++mt) {
    const int rowl = wid * 32 + mt * 16 + quad * 4;
#pragma unroll
    for (int nt = 0; nt < 8; ++nt)
#pragma unroll
      for (int r = 0; r < 4; ++r)
        out[(m0 + rowl + r) * (size_t)HDIM + n0 + nt * 16 + l16] =
            acc[mt][nt][r] * prX[mt][r] * sdp;
  }
}

// ---------------------------------------------------------------------------
extern "C" void kernel_launch(void* const* d_in, const int* in_sizes, int n_in,
                              void* d_out, int out_size, void* d_ws, size_t ws_size,
                              hipStream_t stream) {
  const float* x   = (const float*)d_in[0];
  const void* gw_s = d_in[1];
  const float* gs  = (const float*)d_in[2];
  const void* uw_s = d_in[3];
  const float* us  = (const float*)d_in[4];
  const void* dw_s = d_in[5];
  const float* dsc = (const float*)d_in[6];
  float* out       = (float*)d_out;

  const size_t NW = (size_t)IDIM * HDIM;  // 58,720,256 elements per weight

  unsigned char* ws = (unsigned char*)d_ws;
  unsigned char* xq = ws;                         // 16 MB
  float* xsT = (float*)(ws + 16777216);           // 512 KB
  unsigned char* hq  = ws + 17301504;             // 56 MB
  float* hsT = (float*)(ws + 76021760);           // 1.75 MB
  unsigned char* gwq = ws + 77856768;             // 56 MB
  unsigned char* uwq = ws + 136577024;            // 56 MB
  unsigned char* dwq = gwq;                       // reuse gate slot after dual_gemm
  int* flag = (int*)(ws + 195297280);

  const bool fits = ws_size >= (size_t)195297284;
  const int use_conv = fits ? 1 : 0;

  const int convBlocks = (int)(NW / (16 * 256));  // 14336, exact

  if (fits) {
    detect_dtype<<<1, 64, 0, stream>>>((const unsigned int*)gw_s, flag);
    conv_w<<<convBlocks, 256, 0, stream>>>(gw_s, gwq, flag);
    conv_w<<<convBlocks, 256, 0, stream>>>(uw_s, uwq, flag);
  }
  fq_act<<<(MDIM * (HDIM / 128)) / 4, 256, 0, stream>>>(x, xq, xsT);
  dual_gemm_silu_fq<<<(MDIM / 128) * (IDIM / 128), 256, 0, stream>>>(
      xq, xsT, gwq, (const unsigned char*)gw_s, gs,
      uwq, (const unsigned char*)uw_s, us, hq, hsT, flag, use_conv);
  if (fits) {
    conv_w<<<convBlocks, 256, 0, stream>>>(dw_s, dwq, flag);
  }
  gemm_down<<<(MDIM / 128) * (HDIM / 128), 256, 0, stream>>>(
      hq, hsT, dwq, (const unsigned char*)dw_s, dsc, out, flag, use_conv);
}